// Round 1
// baseline (433.962 us; speedup 1.0000x reference)
//
#include <hip/hip_runtime.h>
#include <hip/hip_bf16.h>

// MultiHeadAttention: B=4, S=4096, D=512, H=2, PD=256, fp32 in/out.
// Strategy: bf16 MFMA (16x16x32) for all matmuls, fp32 accumulate.
// Threshold 5.7e-3 ~ 8*bf16eps*max|ref| -> bf16 inputs admissible.

#define B_  4
#define S_  4096
#define D_  512
#define H_  2
#define PD_ 256
#define NROW (B_*S_)          // 16384

typedef __attribute__((ext_vector_type(4))) float f32x4;
typedef __attribute__((ext_vector_type(8))) short short8;
typedef __attribute__((ext_vector_type(4))) short short4v;

static __device__ __forceinline__ short f2bf(float f) {
  unsigned int u = __float_as_uint(f);
  u += 0x7fffu + ((u >> 16) & 1u);
  return (short)(u >> 16);
}

static __device__ __forceinline__ float rmax16(float v) {
  v = fmaxf(v, __shfl_xor(v, 1));
  v = fmaxf(v, __shfl_xor(v, 2));
  v = fmaxf(v, __shfl_xor(v, 4));
  v = fmaxf(v, __shfl_xor(v, 8));
  return v;
}
static __device__ __forceinline__ float rsum16(float v) {
  v += __shfl_xor(v, 1);
  v += __shfl_xor(v, 2);
  v += __shfl_xor(v, 4);
  v += __shfl_xor(v, 8);
  return v;
}

// ---------------- kernel: convert x (f32) -> bf16 ----------------
__global__ void convert_x_kernel(const float* __restrict__ x, short* __restrict__ xb, int n8) {
  int i = blockIdx.x * blockDim.x + threadIdx.x;
  int stride = gridDim.x * blockDim.x;
  for (; i < n8; i += stride) {
    const f32x4* p = (const f32x4*)(x + (size_t)i * 8);
    f32x4 a = p[0], b = p[1];
    short8 v;
    v[0] = f2bf(a[0]); v[1] = f2bf(a[1]); v[2] = f2bf(a[2]); v[3] = f2bf(a[3]);
    v[4] = f2bf(b[0]); v[5] = f2bf(b[1]); v[6] = f2bf(b[2]); v[7] = f2bf(b[3]);
    *(short8*)(xb + (size_t)i * 8) = v;
  }
}

// ---------------- kernel: transpose W[k][n] f32 -> Wt[n][k] bf16 ----------------
__global__ __launch_bounds__(256) void transpose_w(
    const float* __restrict__ W0, const float* __restrict__ W1,
    const float* __restrict__ W2, const float* __restrict__ W3,
    short* __restrict__ T0, short* __restrict__ T1,
    short* __restrict__ T2, short* __restrict__ T3) {
  const float* W = (blockIdx.z == 0) ? W0 : (blockIdx.z == 1) ? W1 : (blockIdx.z == 2) ? W2 : W3;
  short* T = (blockIdx.z == 0) ? T0 : (blockIdx.z == 1) ? T1 : (blockIdx.z == 2) ? T2 : T3;
  __shared__ float tile[32][33];
  int tx = threadIdx.x & 31, ty = threadIdx.x >> 5;
  int r0 = blockIdx.x * 32, c0 = blockIdx.y * 32;
#pragma unroll
  for (int i = 0; i < 4; ++i)
    tile[ty + 8 * i][tx] = W[(size_t)(r0 + ty + 8 * i) * D_ + c0 + tx];
  __syncthreads();
#pragma unroll
  for (int i = 0; i < 4; ++i)
    T[(size_t)(c0 + ty + 8 * i) * D_ + r0 + tx] = f2bf(tile[tx][ty + 8 * i]);
}

// ---------------- GEMM: C[M,N] = A[M,512](bf16) * Bt[N,512](bf16)^T + bias ----------------
// MODE 0: three weights via blockIdx.z, scatter-write bf16 Q/K/V as [B,H,S,PD]
// MODE 1: single weight, dense f32 out [M,512] + bias
template <int MODE>
__global__ __launch_bounds__(256, 2) void gemm_bt(
    const short* __restrict__ A,
    const short* __restrict__ Bt0, const short* __restrict__ Bt1, const short* __restrict__ Bt2,
    const float* __restrict__ b0, const float* __restrict__ b1, const float* __restrict__ b2,
    short* __restrict__ o0, short* __restrict__ o1, short* __restrict__ o2,
    float* __restrict__ fout) {
  __shared__ short sA[128 * 72];   // 128 rows x (64 k + 8 pad)
  __shared__ short sB[128 * 72];

  const int tid = threadIdx.x;
  const int lane = tid & 63, wid = tid >> 6;
  const int wr = wid >> 1, wc = wid & 1;
  const int l15 = lane & 15, g = lane >> 4;
  const int m0 = blockIdx.x * 128, n0 = blockIdx.y * 128;

  const short* Bt = (MODE == 0) ? ((blockIdx.z == 0) ? Bt0 : (blockIdx.z == 1) ? Bt1 : Bt2) : Bt0;
  const float* bias = (MODE == 0) ? ((blockIdx.z == 0) ? b0 : (blockIdx.z == 1) ? b1 : b2) : b0;

  short8 pa[4], pb[4];   // prefetch registers

  auto loadT = [&](int kt) {
#pragma unroll
    for (int i = 0; i < 4; ++i) {
      int slot = tid + 256 * i;
      int r = slot >> 3, gg = slot & 7;
      pa[i] = *(const short8*)(A + (size_t)(m0 + r) * D_ + kt * 64 + 8 * gg);
      pb[i] = *(const short8*)(Bt + (size_t)(n0 + r) * D_ + kt * 64 + 8 * gg);
    }
  };
  auto storeT = [&]() {
#pragma unroll
    for (int i = 0; i < 4; ++i) {
      int slot = tid + 256 * i;
      int r = slot >> 3, gg = slot & 7;
      *(short8*)&sA[r * 72 + 8 * gg] = pa[i];
      *(short8*)&sB[r * 72 + 8 * gg] = pb[i];
    }
  };

  f32x4 acc[4][4];
#pragma unroll
  for (int i = 0; i < 4; ++i)
#pragma unroll
    for (int j = 0; j < 4; ++j) acc[i][j] = (f32x4)0.0f;

  loadT(0);
#pragma unroll 1
  for (int kt = 0; kt < 8; ++kt) {
    __syncthreads();
    storeT();
    if (kt < 7) loadT(kt + 1);
    __syncthreads();
#pragma unroll
    for (int s = 0; s < 2; ++s) {
      short8 a[4], b[4];
#pragma unroll
      for (int fr = 0; fr < 4; ++fr)
        a[fr] = *(const short8*)&sA[(wr * 64 + fr * 16 + l15) * 72 + 32 * s + 8 * g];
#pragma unroll
      for (int fc = 0; fc < 4; ++fc)
        b[fc] = *(const short8*)&sB[(wc * 64 + fc * 16 + l15) * 72 + 32 * s + 8 * g];
#pragma unroll
      for (int fr = 0; fr < 4; ++fr)
#pragma unroll
        for (int fc = 0; fc < 4; ++fc)
          acc[fr][fc] = __builtin_amdgcn_mfma_f32_16x16x32_bf16(a[fr], b[fc], acc[fr][fc], 0, 0, 0);
    }
  }

  if (MODE == 0) {
    short* dst = (blockIdx.z == 0) ? o0 : (blockIdx.z == 1) ? o1 : o2;
#pragma unroll
    for (int fc = 0; fc < 4; ++fc) {
      int n = n0 + wc * 64 + fc * 16 + l15;
      float bvv = bias[n];
      int h = n >> 8, pd = n & 255;
#pragma unroll
      for (int fr = 0; fr < 4; ++fr)
#pragma unroll
        for (int r = 0; r < 4; ++r) {
          int m = m0 + wr * 64 + fr * 16 + 4 * g + r;
          int bb = m >> 12, ss = m & 4095;
          dst[((size_t)((bb * H_ + h) * S_ + ss)) * PD_ + pd] = f2bf(acc[fr][fc][r] + bvv);
        }
    }
  } else {
#pragma unroll
    for (int fc = 0; fc < 4; ++fc) {
      int n = n0 + wc * 64 + fc * 16 + l15;
      float bvv = bias[n];
#pragma unroll
      for (int fr = 0; fr < 4; ++fr)
#pragma unroll
        for (int r = 0; r < 4; ++r) {
          int m = m0 + wr * 64 + fr * 16 + 4 * g + r;
          fout[(size_t)m * D_ + n] = acc[fr][fc][r] + bvv;
        }
    }
  }
}

// ---------------- flash attention ----------------
// 4 waves/block, wave owns 16 q rows (BQ=64/block), K-tile BK=32, D=PD=256.
// Q hoisted to regs. K in LDS [32][264]. V transposed in LDS [256][40] with
// chunk-XOR swizzle. P via per-wave LDS slice. Online softmax fp32.
__global__ __launch_bounds__(256, 2) void attn_kernel(
    const short* __restrict__ Qw, const short* __restrict__ Kw,
    const short* __restrict__ Vw, short* __restrict__ ATT) {
  __shared__ short sK[32 * 264];        // [krow][d 256+8 pad]
  __shared__ short sVt[256 * 40];       // [d][k 32 + 8 pad], chunk-swizzled
  __shared__ short sP[4 * 16 * 40];     // per-wave [16 q][k 32 + 8 pad]

  const int tid = threadIdx.x, lane = tid & 63, wid = tid >> 6;
  const int l15 = lane & 15, g = lane >> 4;
  const int head = blockIdx.x & 7, qt = blockIdx.x >> 3;   // head->XCD pinning
  const size_t hoff = (size_t)head * S_ * PD_;
  const short* Qh = Qw + hoff;
  const short* Kh = Kw + hoff;
  const short* Vh = Vw + hoff;

  // hoist Q fragments: rows qt*64 + wid*16 + l15, 8 k-steps of 32 over d
  short8 qf[8];
  {
    const short* qp = Qh + (size_t)(qt * 64 + wid * 16 + l15) * PD_;
#pragma unroll
    for (int s = 0; s < 8; ++s) qf[s] = *(const short8*)(qp + 8 * g + 32 * s);
  }

  f32x4 o[16];
#pragma unroll
  for (int i = 0; i < 16; ++i) o[i] = (f32x4)0.0f;
  float m_r[4] = {-1e30f, -1e30f, -1e30f, -1e30f};
  float l_r[4] = {0.f, 0.f, 0.f, 0.f};

  short8 kreg[4], vreg[4];
  auto loadKV = [&](int t) {
    int k0 = t * 32;
#pragma unroll
    for (int i = 0; i < 4; ++i) {
      int slot = tid + 256 * i;
      int r = slot >> 5, gg = slot & 31;
      kreg[i] = *(const short8*)(Kh + (size_t)(k0 + r) * PD_ + 8 * gg);
    }
#pragma unroll
    for (int i = 0; i < 2; ++i) {
      int slot = tid + 256 * i;
      int kp = slot >> 5, dg = slot & 31;
      vreg[2 * i + 0] = *(const short8*)(Vh + (size_t)(k0 + 2 * kp) * PD_ + 8 * dg);
      vreg[2 * i + 1] = *(const short8*)(Vh + (size_t)(k0 + 2 * kp + 1) * PD_ + 8 * dg);
    }
  };
  auto storeKV = [&]() {
#pragma unroll
    for (int i = 0; i < 4; ++i) {
      int slot = tid + 256 * i;
      int r = slot >> 5, gg = slot & 31;
      *(short8*)&sK[r * 264 + 8 * gg] = kreg[i];
    }
#pragma unroll
    for (int i = 0; i < 2; ++i) {
      int slot = tid + 256 * i;
      int kp = slot >> 5, dg = slot & 31;
#pragma unroll
      for (int j = 0; j < 8; ++j) {
        int d = 8 * dg + j;
        int cs = (kp >> 2) ^ ((d >> 3) & 3);   // chunk-XOR swizzle (bank spread)
        unsigned int val = (unsigned int)(unsigned short)vreg[2 * i + 0][j] |
                           ((unsigned int)(unsigned short)vreg[2 * i + 1][j] << 16);
        *(unsigned int*)&sVt[d * 40 + cs * 8 + (kp & 3) * 2] = val;
      }
    }
  };

  loadKV(0);
#pragma unroll 1
  for (int t = 0; t < S_ / 32; ++t) {
    __syncthreads();
    storeKV();
    if (t < S_ / 32 - 1) loadKV(t + 1);
    __syncthreads();

    // S = Q * K^T  (B-frag: col = k-row of tile, dot dim = d)
    f32x4 sacc[2];
    sacc[0] = (f32x4)0.0f; sacc[1] = (f32x4)0.0f;
#pragma unroll
    for (int cf = 0; cf < 2; ++cf)
#pragma unroll
      for (int s = 0; s < 8; ++s) {
        short8 kf = *(const short8*)&sK[(cf * 16 + l15) * 264 + 32 * s + 8 * g];
        sacc[cf] = __builtin_amdgcn_mfma_f32_16x16x32_bf16(qf[s], kf, sacc[cf], 0, 0, 0);
      }

    // online softmax (rows r = 4*g + reg per lane)
    float p0[4], p1[4], resc[4];
#pragma unroll
    for (int r = 0; r < 4; ++r) {
      float s0 = sacc[0][r] * 0.0625f, s1 = sacc[1][r] * 0.0625f;
      float tmax = rmax16(fmaxf(s0, s1));
      float mn = fmaxf(m_r[r], tmax);
      resc[r] = __expf(m_r[r] - mn);
      m_r[r] = mn;
      p0[r] = __expf(s0 - mn);
      p1[r] = __expf(s1 - mn);
      float sum = rsum16(p0[r] + p1[r]);
      l_r[r] = l_r[r] * resc[r] + sum;
    }
    // write P to per-wave LDS slice (bf16)
#pragma unroll
    for (int r = 0; r < 4; ++r) {
      sP[(wid * 16 + 4 * g + r) * 40 + l15] = f2bf(p0[r]);
      sP[(wid * 16 + 4 * g + r) * 40 + 16 + l15] = f2bf(p1[r]);
    }
    // rescale O (exact skip when no row max changed: resc == 1)
    if (__any(resc[0] < 1.f || resc[1] < 1.f || resc[2] < 1.f || resc[3] < 1.f)) {
#pragma unroll
      for (int df = 0; df < 16; ++df)
#pragma unroll
        for (int r = 0; r < 4; ++r) o[df][r] *= resc[r];
    }

    // O += P * V   (A-frag = P rows, B-frag = V cols via transposed sVt)
    short8 pf = *(const short8*)&sP[(wid * 16 + l15) * 40 + 8 * g];
#pragma unroll
    for (int df = 0; df < 16; ++df) {
      int d = df * 16 + l15;
      int cs = g ^ ((d >> 3) & 3);
      short8 vf = *(const short8*)&sVt[d * 40 + cs * 8];
      o[df] = __builtin_amdgcn_mfma_f32_16x16x32_bf16(pf, vf, o[df], 0, 0, 0);
    }
  }

  // epilogue: normalize and write merged-head bf16 [B*S, 512]
  float inv[4];
#pragma unroll
  for (int r = 0; r < 4; ++r) inv[r] = 1.0f / l_r[r];
  int bb = head >> 1, hh = head & 1;
#pragma unroll
  for (int df = 0; df < 16; ++df)
#pragma unroll
    for (int r = 0; r < 4; ++r) {
      int qrow = qt * 64 + wid * 16 + 4 * g + r;
      ATT[((size_t)(bb * S_ + qrow)) * D_ + hh * PD_ + df * 16 + l15] = f2bf(o[df][r] * inv[r]);
    }
}

// ---------------- launcher ----------------
extern "C" void kernel_launch(void* const* d_in, const int* in_sizes, int n_in,
                              void* d_out, int out_size, void* d_ws, size_t ws_size,
                              hipStream_t stream) {
  const float* x  = (const float*)d_in[0];
  const float* Wq = (const float*)d_in[1];
  const float* bq = (const float*)d_in[2];
  const float* Wk = (const float*)d_in[3];
  const float* bk = (const float*)d_in[4];
  const float* Wv = (const float*)d_in[5];
  const float* bv = (const float*)d_in[6];
  const float* Wo = (const float*)d_in[7];
  const float* bo = (const float*)d_in[8];
  float* out = (float*)d_out;

  char* ws = (char*)d_ws;
  const size_t WSZ = (size_t)D_ * D_ * 2;          // 512KB per transposed weight
  const size_t QSZ = (size_t)B_ * H_ * S_ * PD_ * 2;  // 16.78MB
  short* wtq = (short*)(ws);
  short* wtk = (short*)(ws + WSZ);
  short* wtv = (short*)(ws + 2 * WSZ);
  short* wto = (short*)(ws + 3 * WSZ);
  short* Qw  = (short*)(ws + 4 * WSZ);
  short* Kw  = (short*)(ws + 4 * WSZ + QSZ);
  short* Vw  = (short*)(ws + 4 * WSZ + 2 * QSZ);
  short* ATT = (short*)(ws + 4 * WSZ + 3 * QSZ);   // also used as xb (dead before attn writes)
  short* XB  = ATT;

  convert_x_kernel<<<dim3(2048), dim3(256), 0, stream>>>(x, XB, (B_ * S_ * D_) / 8);
  transpose_w<<<dim3(16, 16, 4), dim3(256), 0, stream>>>(Wq, Wk, Wv, Wo, wtq, wtk, wtv, wto);
  gemm_bt<0><<<dim3(128, 4, 3), dim3(256), 0, stream>>>(
      XB, wtq, wtk, wtv, bq, bk, bv, Qw, Kw, Vw, (float*)nullptr);
  attn_kernel<<<dim3(512), dim3(256), 0, stream>>>(Qw, Kw, Vw, ATT);
  gemm_bt<1><<<dim3(128, 4, 1), dim3(256), 0, stream>>>(
      ATT, wto, wto, wto, bo, bo, bo, nullptr, nullptr, nullptr, out);
}

// Round 2
// 304.570 us; speedup vs baseline: 1.4248x; 1.4248x over previous
//
#include <hip/hip_runtime.h>
#include <hip/hip_bf16.h>

// MultiHeadAttention: B=4, S=4096, D=512, H=2, PD=256, fp32 in/out.
// R2: attn rewritten to 32x32x16 swapped-QK flash attention, in-register
// softmax, global_load_lds staging with XOR-swizzled LDS (conflict-free),
// V pre-transposed in global (scratch = d_out region).

#define B_  4
#define S_  4096
#define D_  512
#define H_  2
#define PD_ 256

typedef __attribute__((ext_vector_type(4))) float f32x4;
typedef __attribute__((ext_vector_type(16))) float f32x16;
typedef __attribute__((ext_vector_type(8))) short short8;
typedef __attribute__((ext_vector_type(4))) short short4v;
typedef __attribute__((ext_vector_type(4))) unsigned u32x4;

static __device__ __forceinline__ short f2bf(float f) {
  unsigned u = __float_as_uint(f);
  u += 0x7fffu + ((u >> 16) & 1u);
  return (short)(u >> 16);
}
static __device__ __forceinline__ unsigned pack2(float a, float b) {
  return (unsigned)(unsigned short)f2bf(a) | ((unsigned)(unsigned short)f2bf(b) << 16);
}
static __device__ __forceinline__ void gload16(const short* g, short* l) {
  __builtin_amdgcn_global_load_lds((const __attribute__((address_space(1))) void*)g,
                                   (__attribute__((address_space(3))) void*)l,
                                   16, 0, 0);
}

// ---------------- kernel: convert x (f32) -> bf16 ----------------
__global__ void convert_x_kernel(const float* __restrict__ x, short* __restrict__ xb, int n8) {
  int i = blockIdx.x * blockDim.x + threadIdx.x;
  int stride = gridDim.x * blockDim.x;
  for (; i < n8; i += stride) {
    const f32x4* p = (const f32x4*)(x + (size_t)i * 8);
    f32x4 a = p[0], b = p[1];
    short8 v;
    v[0] = f2bf(a[0]); v[1] = f2bf(a[1]); v[2] = f2bf(a[2]); v[3] = f2bf(a[3]);
    v[4] = f2bf(b[0]); v[5] = f2bf(b[1]); v[6] = f2bf(b[2]); v[7] = f2bf(b[3]);
    *(short8*)(xb + (size_t)i * 8) = v;
  }
}

// ---------------- kernel: transpose W[k][n] f32 -> Wt[n][k] bf16 ----------------
__global__ __launch_bounds__(256) void transpose_w(
    const float* __restrict__ W0, const float* __restrict__ W1,
    const float* __restrict__ W2, const float* __restrict__ W3,
    short* __restrict__ T0, short* __restrict__ T1,
    short* __restrict__ T2, short* __restrict__ T3) {
  const float* W = (blockIdx.z == 0) ? W0 : (blockIdx.z == 1) ? W1 : (blockIdx.z == 2) ? W2 : W3;
  short* T = (blockIdx.z == 0) ? T0 : (blockIdx.z == 1) ? T1 : (blockIdx.z == 2) ? T2 : T3;
  __shared__ float tile[32][33];
  int tx = threadIdx.x & 31, ty = threadIdx.x >> 5;
  int r0 = blockIdx.x * 32, c0 = blockIdx.y * 32;
#pragma unroll
  for (int i = 0; i < 4; ++i)
    tile[ty + 8 * i][tx] = W[(size_t)(r0 + ty + 8 * i) * D_ + c0 + tx];
  __syncthreads();
#pragma unroll
  for (int i = 0; i < 4; ++i)
    T[(size_t)(c0 + ty + 8 * i) * D_ + r0 + tx] = f2bf(tile[tx][ty + 8 * i]);
}

// ---------------- kernel: transpose V (bf16) -> Vt[h][d][s], chunk-XOR pre-swizzled ----
// Vt position swizzle within each 64-key granule: pos_chunk = (s>>3 & 7) ^ (d & 7)
__global__ __launch_bounds__(256) void transpose_v(
    const short* __restrict__ Vw, short* __restrict__ Vt) {
  __shared__ short tile[64][68];
  int h = blockIdx.z;
  int s0 = blockIdx.x * 64, d0 = blockIdx.y * 64;
  const short* src = Vw + (size_t)h * S_ * PD_;
  short* dst = Vt + (size_t)h * S_ * PD_;
  int tx = threadIdx.x & 15, ty = threadIdx.x >> 4;
#pragma unroll
  for (int i = 0; i < 4; ++i) {
    short4v v = *(const short4v*)(src + (size_t)(s0 + ty + 16 * i) * PD_ + d0 + tx * 4);
    *(short4v*)&tile[ty + 16 * i][tx * 4] = v;
  }
  __syncthreads();
#pragma unroll
  for (int i = 0; i < 4; ++i) {
    int d = d0 + ty + 16 * i;
    short4v v;
#pragma unroll
    for (int j = 0; j < 4; ++j) v[j] = tile[tx * 4 + j][ty + 16 * i];
    int swz = (tx >> 1) ^ (d & 7);          // chunk index XOR
    *(short4v*)(dst + (size_t)d * S_ + s0 + (tx & 1) * 4 + swz * 8) = v;
  }
}

// ---------------- GEMM: C[M,N] = A[M,512](bf16) * Bt[N,512](bf16)^T + bias ----------------
// MODE 0: three weights via blockIdx.z, scatter-write bf16 Q/K/V as [B,H,S,PD]
//         z==1 (K) additionally chunk-XOR pre-swizzles the d index by (s&7).
// MODE 1: single weight, dense f32 out [M,512] + bias
template <int MODE>
__global__ __launch_bounds__(256, 2) void gemm_bt(
    const short* __restrict__ A,
    const short* __restrict__ Bt0, const short* __restrict__ Bt1, const short* __restrict__ Bt2,
    const float* __restrict__ b0, const float* __restrict__ b1, const float* __restrict__ b2,
    short* __restrict__ o0, short* __restrict__ o1, short* __restrict__ o2,
    float* __restrict__ fout) {
  __shared__ short sA[128 * 72];
  __shared__ short sB[128 * 72];

  const int tid = threadIdx.x;
  const int lane = tid & 63, wid = tid >> 6;
  const int wr = wid >> 1, wc = wid & 1;
  const int l15 = lane & 15, g = lane >> 4;
  const int m0 = blockIdx.x * 128, n0 = blockIdx.y * 128;

  const short* Bt = (MODE == 0) ? ((blockIdx.z == 0) ? Bt0 : (blockIdx.z == 1) ? Bt1 : Bt2) : Bt0;
  const float* bias = (MODE == 0) ? ((blockIdx.z == 0) ? b0 : (blockIdx.z == 1) ? b1 : b2) : b0;

  short8 pa[4], pb[4];

  auto loadT = [&](int kt) {
#pragma unroll
    for (int i = 0; i < 4; ++i) {
      int slot = tid + 256 * i;
      int r = slot >> 3, gg = slot & 7;
      pa[i] = *(const short8*)(A + (size_t)(m0 + r) * D_ + kt * 64 + 8 * gg);
      pb[i] = *(const short8*)(Bt + (size_t)(n0 + r) * D_ + kt * 64 + 8 * gg);
    }
  };
  auto storeT = [&]() {
#pragma unroll
    for (int i = 0; i < 4; ++i) {
      int slot = tid + 256 * i;
      int r = slot >> 3, gg = slot & 7;
      *(short8*)&sA[r * 72 + 8 * gg] = pa[i];
      *(short8*)&sB[r * 72 + 8 * gg] = pb[i];
    }
  };

  f32x4 acc[4][4];
#pragma unroll
  for (int i = 0; i < 4; ++i)
#pragma unroll
    for (int j = 0; j < 4; ++j) acc[i][j] = (f32x4)0.0f;

  loadT(0);
#pragma unroll 1
  for (int kt = 0; kt < 8; ++kt) {
    __syncthreads();
    storeT();
    if (kt < 7) loadT(kt + 1);
    __syncthreads();
#pragma unroll
    for (int s = 0; s < 2; ++s) {
      short8 a[4], b[4];
#pragma unroll
      for (int fr = 0; fr < 4; ++fr)
        a[fr] = *(const short8*)&sA[(wr * 64 + fr * 16 + l15) * 72 + 32 * s + 8 * g];
#pragma unroll
      for (int fc = 0; fc < 4; ++fc)
        b[fc] = *(const short8*)&sB[(wc * 64 + fc * 16 + l15) * 72 + 32 * s + 8 * g];
#pragma unroll
      for (int fr = 0; fr < 4; ++fr)
#pragma unroll
        for (int fc = 0; fc < 4; ++fc)
          acc[fr][fc] = __builtin_amdgcn_mfma_f32_16x16x32_bf16(a[fr], b[fc], acc[fr][fc], 0, 0, 0);
    }
  }

  if (MODE == 0) {
    short* dst = (blockIdx.z == 0) ? o0 : (blockIdx.z == 1) ? o1 : o2;
    const bool kswz = (blockIdx.z == 1);
#pragma unroll
    for (int fc = 0; fc < 4; ++fc) {
      int n = n0 + wc * 64 + fc * 16 + l15;
      float bvv = bias[n];
      int h = n >> 8, pd = n & 255;
#pragma unroll
      for (int fr = 0; fr < 4; ++fr)
#pragma unroll
        for (int r = 0; r < 4; ++r) {
          int m = m0 + wr * 64 + fr * 16 + 4 * g + r;
          int bb = m >> 12, ss = m & 4095;
          int pdw = pd;
          if (kswz) {
            int ch = pd >> 3;
            pdw = (pd & 7) | (((ch & 24) | ((ch & 7) ^ (ss & 7))) << 3);
          }
          dst[((size_t)((bb * H_ + h) * S_ + ss)) * PD_ + pdw] = f2bf(acc[fr][fc][r] + bvv);
        }
    }
  } else {
#pragma unroll
    for (int fc = 0; fc < 4; ++fc) {
      int n = n0 + wc * 64 + fc * 16 + l15;
      float bvv = bias[n];
#pragma unroll
      for (int fr = 0; fr < 4; ++fr)
#pragma unroll
        for (int r = 0; r < 4; ++r) {
          int m = m0 + wr * 64 + fr * 16 + 4 * g + r;
          fout[(size_t)m * D_ + n] = acc[fr][fc][r] + bvv;
        }
    }
  }
}

// ---------------- flash attention, 32x32x16 swapped-QK ----------------
// 4 waves x 32 q-rows = 128 q/block; 256 blocks (32 qt x 8 heads, head = bid&7).
// BK = 64 keys/tile. K,V staged via global_load_lds into double-buffered LDS
// (linear dest; XOR swizzle pre-applied in global layouts). Softmax in-register.
__global__ __launch_bounds__(256, 1) void attn2_kernel(
    const short* __restrict__ Qw, const short* __restrict__ Kw,
    const short* __restrict__ Vt, short* __restrict__ ATT) {
  __shared__ short sK[2][64 * 256];   // [key][d], chunk-XOR by (key&7)
  __shared__ short sV[2][256 * 64];   // [d][key], chunk-XOR by (d&7)
  __shared__ float sR[4][32];         // per-wave broadcast of resc / 1/l

  const int tid  = threadIdx.x;
  const int lane = tid & 63;
  const int w    = tid >> 6;
  const int l31  = lane & 31;
  const int hi   = lane >> 5;
  const int head = blockIdx.x & 7, qt = blockIdx.x >> 3;
  const size_t hoff = (size_t)head * S_ * PD_;
  const short* Qh = Qw + hoff;
  const short* Kh = Kw + hoff;
  const short* Vh = Vt + hoff;        // [PD][S]
  const int wbase = tid & ~63;        // wave-uniform LDS slot base

  // Q fragments (B-operand of swapped QK): Q[qrow][dc*16 + hi*8 + j]
  const int qrow = qt * 128 + w * 32 + l31;
  short8 qf[16];
#pragma unroll
  for (int dc = 0; dc < 16; ++dc)
    qf[dc] = *(const short8*)(Qh + (size_t)qrow * PD_ + dc * 16 + hi * 8);

  f32x16 o[8];
#pragma unroll
  for (int i = 0; i < 8; ++i) o[i] = (f32x16)0.0f;
  float mrun = -3.0e38f, lrun = 0.0f;

  auto stage = [&](int buf, int t) {
    const short* kp = Kh + (size_t)t * 64 * PD_;
#pragma unroll
    for (int i = 0; i < 8; ++i) {
      int slot = tid + 256 * i;
      gload16(kp + (slot >> 5) * PD_ + (slot & 31) * 8, &sK[buf][(wbase + 256 * i) * 8]);
    }
    const short* vp = Vh + t * 64;
#pragma unroll
    for (int i = 0; i < 8; ++i) {
      int slot = tid + 256 * i;
      gload16(vp + (size_t)(slot >> 3) * S_ + (slot & 7) * 8, &sV[buf][(wbase + 256 * i) * 8]);
    }
  };

  stage(0, 0);
  const int NT = S_ / 64;
#pragma unroll 1
  for (int t = 0; t < NT; ++t) {
    __syncthreads();   // implicit vmcnt(0): buf[t&1] ready; all waves done with buf[(t+1)&1]
    const int buf = t & 1;
    if (t + 1 < NT) stage(buf ^ 1, t + 1);

    // ---- QK^T (swapped): St[key][q], 2 key-blocks of 32
    f32x16 sacc[2];
    sacc[0] = (f32x16)0.0f; sacc[1] = (f32x16)0.0f;
#pragma unroll
    for (int dc = 0; dc < 16; ++dc) {
      int ch = (2 * dc + hi) ^ (l31 & 7);
      short8 kf0 = *(const short8*)&sK[buf][l31 * 256 + ch * 8];
      sacc[0] = __builtin_amdgcn_mfma_f32_32x32x16_bf16(kf0, qf[dc], sacc[0], 0, 0, 0);
      short8 kf1 = *(const short8*)&sK[buf][(32 + l31) * 256 + ch * 8];
      sacc[1] = __builtin_amdgcn_mfma_f32_32x32x16_bf16(kf1, qf[dc], sacc[1], 0, 0, 0);
    }

    // ---- online softmax: lane holds 32 of 64 key-scores for q = l31 (partner has rest)
    float tmax = sacc[0][0];
#pragma unroll
    for (int r = 1; r < 16; ++r) tmax = fmaxf(tmax, sacc[0][r]);
#pragma unroll
    for (int r = 0; r < 16; ++r) tmax = fmaxf(tmax, sacc[1][r]);
    tmax = fmaxf(tmax, __shfl_xor(tmax, 32));
    const bool skip = __all(tmax <= mrun);   // exact skip: no row max changed
    if (!skip) {
      float mn = fmaxf(mrun, tmax);
      float resc = __expf((mrun - mn) * 0.0625f);
      mrun = mn;
      lrun *= resc;
      if (!hi) sR[w][l31] = resc;            // broadcast resc[q] to o-layout lanes
      asm volatile("" ::: "memory");
      f32x4 rv0 = *(const f32x4*)&sR[w][0 + hi * 4];
      f32x4 rv1 = *(const f32x4*)&sR[w][8 + hi * 4];
      f32x4 rv2 = *(const f32x4*)&sR[w][16 + hi * 4];
      f32x4 rv3 = *(const f32x4*)&sR[w][24 + hi * 4];
#pragma unroll
      for (int dcb = 0; dcb < 8; ++dcb)
#pragma unroll
        for (int r = 0; r < 16; ++r) {
          float rr = (r < 4 ? rv0 : r < 8 ? rv1 : r < 12 ? rv2 : rv3)[r & 3];
          o[dcb][r] *= rr;
        }
    }
    float lsum = 0.0f;
#pragma unroll
    for (int kb = 0; kb < 2; ++kb)
#pragma unroll
      for (int r = 0; r < 16; ++r) {
        float p = __expf((sacc[kb][r] - mrun) * 0.0625f);
        sacc[kb][r] = p;
        lsum += p;
      }
    lsum += __shfl_xor(lsum, 32);
    lrun += lsum;

    // ---- P repack (bf16, cross-hi exchange) + PV
#pragma unroll
    for (int kb = 0; kb < 2; ++kb)
#pragma unroll
      for (int c = 0; c < 2; ++c) {
        unsigned pk0 = pack2(sacc[kb][8 * c + 0], sacc[kb][8 * c + 1]);
        unsigned pk1 = pack2(sacc[kb][8 * c + 2], sacc[kb][8 * c + 3]);
        unsigned pk2 = pack2(sacc[kb][8 * c + 4], sacc[kb][8 * c + 5]);
        unsigned pk3 = pack2(sacc[kb][8 * c + 6], sacc[kb][8 * c + 7]);
        unsigned sh0 = __shfl_xor(pk0, 32);
        unsigned sh1 = __shfl_xor(pk1, 32);
        unsigned sh2 = __shfl_xor(pk2, 32);
        unsigned sh3 = __shfl_xor(pk3, 32);
        u32x4 ua;
        ua[0] = hi ? sh2 : pk0;
        ua[1] = hi ? sh3 : pk1;
        ua[2] = hi ? pk2 : sh0;
        ua[3] = hi ? pk3 : sh1;
        short8 af = *(short8*)&ua;
        const int kc = kb * 2 + c;
#pragma unroll
        for (int dcb = 0; dcb < 8; ++dcb) {
          int d = dcb * 32 + l31;
          int ch = (2 * kc + hi) ^ (d & 7);
          short8 vf = *(const short8*)&sV[buf][d * 64 + ch * 8];
          o[dcb] = __builtin_amdgcn_mfma_f32_32x32x16_bf16(af, vf, o[dcb], 0, 0, 0);
        }
      }
  }

  // ---- epilogue: normalize and write merged-head bf16 [B*S, 512]
  if (!hi) sR[w][l31] = 1.0f / lrun;
  asm volatile("" ::: "memory");
  f32x4 iv0 = *(const f32x4*)&sR[w][0 + hi * 4];
  f32x4 iv1 = *(const f32x4*)&sR[w][8 + hi * 4];
  f32x4 iv2 = *(const f32x4*)&sR[w][16 + hi * 4];
  f32x4 iv3 = *(const f32x4*)&sR[w][24 + hi * 4];
  const int bb = head >> 1, hh = head & 1;
#pragma unroll
  for (int r = 0; r < 16; ++r) {
    int q = qt * 128 + w * 32 + (r & 3) + 8 * (r >> 2) + 4 * hi;
    float iv = (r < 4 ? iv0 : r < 8 ? iv1 : r < 12 ? iv2 : iv3)[r & 3];
    size_t base = ((size_t)(bb * S_ + q)) * D_ + hh * PD_;
#pragma unroll
    for (int dcb = 0; dcb < 8; ++dcb)
      ATT[base + dcb * 32 + l31] = f2bf(o[dcb][r] * iv);
  }
}

// ---------------- launcher ----------------
extern "C" void kernel_launch(void* const* d_in, const int* in_sizes, int n_in,
                              void* d_out, int out_size, void* d_ws, size_t ws_size,
                              hipStream_t stream) {
  const float* x  = (const float*)d_in[0];
  const float* Wq = (const float*)d_in[1];
  const float* bq = (const float*)d_in[2];
  const float* Wk = (const float*)d_in[3];
  const float* bk = (const float*)d_in[4];
  const float* Wv = (const float*)d_in[5];
  const float* bv = (const float*)d_in[6];
  const float* Wo = (const float*)d_in[7];
  const float* bo = (const float*)d_in[8];
  float* out = (float*)d_out;

  char* ws = (char*)d_ws;
  const size_t WSZ = (size_t)D_ * D_ * 2;             // 512KB per transposed weight
  const size_t QSZ = (size_t)B_ * H_ * S_ * PD_ * 2;  // 16.78MB
  short* wtq = (short*)(ws);
  short* wtk = (short*)(ws + WSZ);
  short* wtv = (short*)(ws + 2 * WSZ);
  short* wto = (short*)(ws + 3 * WSZ);
  short* Qw  = (short*)(ws + 4 * WSZ);
  short* Kw  = (short*)(ws + 4 * WSZ + QSZ);
  short* Vw  = (short*)(ws + 4 * WSZ + 2 * QSZ);
  short* ATT = (short*)(ws + 4 * WSZ + 3 * QSZ);  // also used as xb (dead before attn writes)
  short* XB  = ATT;
  short* Vtp = (short*)d_out;  // V^T scratch lives in d_out; overwritten by final GEMM

  convert_x_kernel<<<dim3(2048), dim3(256), 0, stream>>>(x, XB, (B_ * S_ * D_) / 8);
  transpose_w<<<dim3(16, 16, 4), dim3(256), 0, stream>>>(Wq, Wk, Wv, Wo, wtq, wtk, wtv, wto);
  gemm_bt<0><<<dim3(128, 4, 3), dim3(256), 0, stream>>>(
      XB, wtq, wtk, wtv, bq, bk, bv, Qw, Kw, Vw, (float*)nullptr);
  transpose_v<<<dim3(64, 4, 8), dim3(256), 0, stream>>>(Vw, Vtp);
  attn2_kernel<<<dim3(256), dim3(256), 0, stream>>>(Qw, Kw, Vtp, ATT);
  gemm_bt<1><<<dim3(128, 4, 1), dim3(256), 0, stream>>>(
      ATT, wto, wto, wto, bo, bo, bo, nullptr, nullptr, nullptr, out);
}

// Round 3
// 292.586 us; speedup vs baseline: 1.4832x; 1.0410x over previous
//
#include <hip/hip_runtime.h>
#include <hip/hip_bf16.h>

// MultiHeadAttention: B=4, S=4096, D=512, H=2, PD=256, fp32 in/out.
// R3: attn split-K wave pairs (waves 0,1 = key-half 0; waves 2,3 = key-half 1),
// BK=32 single-buffered per half -> 68KB LDS -> 2 blocks/CU (2 waves/SIMD).
// In-block merge of (m,l,o) at the end. Defer-max THR=16.

#define B_  4
#define S_  4096
#define D_  512
#define H_  2
#define PD_ 256
#define SC2 0.09016844f   // (1/16) * log2(e)

typedef __attribute__((ext_vector_type(4))) float f32x4;
typedef __attribute__((ext_vector_type(16))) float f32x16;
typedef __attribute__((ext_vector_type(8))) short short8;
typedef __attribute__((ext_vector_type(4))) short short4v;
typedef __attribute__((ext_vector_type(4))) unsigned u32x4;

static __device__ __forceinline__ short f2bf(float f) {
  unsigned u = __float_as_uint(f);
  u += 0x7fffu + ((u >> 16) & 1u);
  return (short)(u >> 16);
}
static __device__ __forceinline__ unsigned pack2(float a, float b) {
  return (unsigned)(unsigned short)f2bf(a) | ((unsigned)(unsigned short)f2bf(b) << 16);
}
static __device__ __forceinline__ void gload16(const short* g, short* l) {
  __builtin_amdgcn_global_load_lds((const __attribute__((address_space(1))) void*)g,
                                   (__attribute__((address_space(3))) void*)l,
                                   16, 0, 0);
}

// ---------------- kernel: convert x (f32) -> bf16 ----------------
__global__ void convert_x_kernel(const float* __restrict__ x, short* __restrict__ xb, int n8) {
  int i = blockIdx.x * blockDim.x + threadIdx.x;
  int stride = gridDim.x * blockDim.x;
  for (; i < n8; i += stride) {
    const f32x4* p = (const f32x4*)(x + (size_t)i * 8);
    f32x4 a = p[0], b = p[1];
    short8 v;
    v[0] = f2bf(a[0]); v[1] = f2bf(a[1]); v[2] = f2bf(a[2]); v[3] = f2bf(a[3]);
    v[4] = f2bf(b[0]); v[5] = f2bf(b[1]); v[6] = f2bf(b[2]); v[7] = f2bf(b[3]);
    *(short8*)(xb + (size_t)i * 8) = v;
  }
}

// ---------------- kernel: transpose W[k][n] f32 -> Wt[n][k] bf16 ----------------
__global__ __launch_bounds__(256) void transpose_w(
    const float* __restrict__ W0, const float* __restrict__ W1,
    const float* __restrict__ W2, const float* __restrict__ W3,
    short* __restrict__ T0, short* __restrict__ T1,
    short* __restrict__ T2, short* __restrict__ T3) {
  const float* W = (blockIdx.z == 0) ? W0 : (blockIdx.z == 1) ? W1 : (blockIdx.z == 2) ? W2 : W3;
  short* T = (blockIdx.z == 0) ? T0 : (blockIdx.z == 1) ? T1 : (blockIdx.z == 2) ? T2 : T3;
  __shared__ float tile[32][33];
  int tx = threadIdx.x & 31, ty = threadIdx.x >> 5;
  int r0 = blockIdx.x * 32, c0 = blockIdx.y * 32;
#pragma unroll
  for (int i = 0; i < 4; ++i)
    tile[ty + 8 * i][tx] = W[(size_t)(r0 + ty + 8 * i) * D_ + c0 + tx];
  __syncthreads();
#pragma unroll
  for (int i = 0; i < 4; ++i)
    T[(size_t)(c0 + ty + 8 * i) * D_ + r0 + tx] = f2bf(tile[tx][ty + 8 * i]);
}

// ---------------- kernel: transpose V (bf16) -> Vt[h][d][s] ----------------
// chunk-XOR pre-swizzle within each 32-key granule: pos = ((s>>3)&3) ^ ((d>>1)&3)
__global__ __launch_bounds__(256) void transpose_v(
    const short* __restrict__ Vw, short* __restrict__ Vt) {
  __shared__ short tile[64][68];
  int h = blockIdx.z;
  int s0 = blockIdx.x * 64, d0 = blockIdx.y * 64;
  const short* src = Vw + (size_t)h * S_ * PD_;
  short* dst = Vt + (size_t)h * S_ * PD_;
  int tx = threadIdx.x & 15, ty = threadIdx.x >> 4;
#pragma unroll
  for (int i = 0; i < 4; ++i) {
    short4v v = *(const short4v*)(src + (size_t)(s0 + ty + 16 * i) * PD_ + d0 + tx * 4);
    *(short4v*)&tile[ty + 16 * i][tx * 4] = v;
  }
  __syncthreads();
#pragma unroll
  for (int i = 0; i < 4; ++i) {
    int d = d0 + ty + 16 * i;
    short4v v;
#pragma unroll
    for (int j = 0; j < 4; ++j) v[j] = tile[tx * 4 + j][ty + 16 * i];
    int swz = ((tx >> 1) & 3) ^ ((d >> 1) & 3);   // chunk pos within 32-granule
    *(short4v*)(dst + (size_t)d * S_ + s0 + (tx >> 3) * 32 + swz * 8 + (tx & 1) * 4) = v;
  }
}

// ---------------- GEMM: C[M,N] = A[M,512](bf16) * Bt[N,512](bf16)^T + bias ----------------
template <int MODE>
__global__ __launch_bounds__(256, 2) void gemm_bt(
    const short* __restrict__ A,
    const short* __restrict__ Bt0, const short* __restrict__ Bt1, const short* __restrict__ Bt2,
    const float* __restrict__ b0, const float* __restrict__ b1, const float* __restrict__ b2,
    short* __restrict__ o0, short* __restrict__ o1, short* __restrict__ o2,
    float* __restrict__ fout) {
  __shared__ short sA[128 * 72];
  __shared__ short sB[128 * 72];

  const int tid = threadIdx.x;
  const int lane = tid & 63, wid = tid >> 6;
  const int wr = wid >> 1, wc = wid & 1;
  const int l15 = lane & 15, g = lane >> 4;
  const int m0 = blockIdx.x * 128, n0 = blockIdx.y * 128;

  const short* Bt = (MODE == 0) ? ((blockIdx.z == 0) ? Bt0 : (blockIdx.z == 1) ? Bt1 : Bt2) : Bt0;
  const float* bias = (MODE == 0) ? ((blockIdx.z == 0) ? b0 : (blockIdx.z == 1) ? b1 : b2) : b0;

  short8 pa[4], pb[4];

  auto loadT = [&](int kt) {
#pragma unroll
    for (int i = 0; i < 4; ++i) {
      int slot = tid + 256 * i;
      int r = slot >> 3, gg = slot & 7;
      pa[i] = *(const short8*)(A + (size_t)(m0 + r) * D_ + kt * 64 + 8 * gg);
      pb[i] = *(const short8*)(Bt + (size_t)(n0 + r) * D_ + kt * 64 + 8 * gg);
    }
  };
  auto storeT = [&]() {
#pragma unroll
    for (int i = 0; i < 4; ++i) {
      int slot = tid + 256 * i;
      int r = slot >> 3, gg = slot & 7;
      *(short8*)&sA[r * 72 + 8 * gg] = pa[i];
      *(short8*)&sB[r * 72 + 8 * gg] = pb[i];
    }
  };

  f32x4 acc[4][4];
#pragma unroll
  for (int i = 0; i < 4; ++i)
#pragma unroll
    for (int j = 0; j < 4; ++j) acc[i][j] = (f32x4)0.0f;

  loadT(0);
#pragma unroll 1
  for (int kt = 0; kt < 8; ++kt) {
    __syncthreads();
    storeT();
    if (kt < 7) loadT(kt + 1);
    __syncthreads();
#pragma unroll
    for (int s = 0; s < 2; ++s) {
      short8 a[4], b[4];
#pragma unroll
      for (int fr = 0; fr < 4; ++fr)
        a[fr] = *(const short8*)&sA[(wr * 64 + fr * 16 + l15) * 72 + 32 * s + 8 * g];
#pragma unroll
      for (int fc = 0; fc < 4; ++fc)
        b[fc] = *(const short8*)&sB[(wc * 64 + fc * 16 + l15) * 72 + 32 * s + 8 * g];
#pragma unroll
      for (int fr = 0; fr < 4; ++fr)
#pragma unroll
        for (int fc = 0; fc < 4; ++fc)
          acc[fr][fc] = __builtin_amdgcn_mfma_f32_16x16x32_bf16(a[fr], b[fc], acc[fr][fc], 0, 0, 0);
    }
  }

  if (MODE == 0) {
    short* dst = (blockIdx.z == 0) ? o0 : (blockIdx.z == 1) ? o1 : o2;
    const bool kswz = (blockIdx.z == 1);
#pragma unroll
    for (int fc = 0; fc < 4; ++fc) {
      int n = n0 + wc * 64 + fc * 16 + l15;
      float bvv = bias[n];
      int h = n >> 8, pd = n & 255;
#pragma unroll
      for (int fr = 0; fr < 4; ++fr)
#pragma unroll
        for (int r = 0; r < 4; ++r) {
          int m = m0 + wr * 64 + fr * 16 + 4 * g + r;
          int bb = m >> 12, ss = m & 4095;
          int pdw = pd;
          if (kswz) {
            int ch = pd >> 3;
            pdw = (pd & 7) | (((ch & 24) | ((ch & 7) ^ (ss & 7))) << 3);
          }
          dst[((size_t)((bb * H_ + h) * S_ + ss)) * PD_ + pdw] = f2bf(acc[fr][fc][r] + bvv);
        }
    }
  } else {
#pragma unroll
    for (int fc = 0; fc < 4; ++fc) {
      int n = n0 + wc * 64 + fc * 16 + l15;
      float bvv = bias[n];
#pragma unroll
      for (int fr = 0; fr < 4; ++fr)
#pragma unroll
        for (int r = 0; r < 4; ++r) {
          int m = m0 + wr * 64 + fr * 16 + 4 * g + r;
          fout[(size_t)m * D_ + n] = acc[fr][fc][r] + bvv;
        }
    }
  }
}

// ---------------- flash attention, split-K wave pairs ----------------
// Block: 4 waves, 64 q-rows. Wave w: key-half kh=w>>1, q-col qc=w&1 (32 q).
// BK=32, single-buffered per half (16K K + 16K V per half = 64KB total).
// Grid 512 = 64 q-tiles x 8 heads (head = bid&7 -> XCD pin). 2 blocks/CU.
__global__ __launch_bounds__(256, 2) void attn3_kernel(
    const short* __restrict__ Qw, const short* __restrict__ Kw,
    const short* __restrict__ Vt, short* __restrict__ ATT) {
  __shared__ __align__(16) char smem[66560];   // staging 64KB; merge 2x33280B
  __shared__ float sB1[4][32];                 // per-wave broadcast (resc / inv-l)
  __shared__ float sMm[4][32];                 // m exchange
  __shared__ float sMl[2][32];                 // partner l
  short* sK0 = (short*)smem;                   // [32 key][256 d] 16KB
  short* sK1 = (short*)(smem + 16384);
  short* sV0 = (short*)(smem + 32768);         // [256 d][32 key] 16KB
  short* sV1 = (short*)(smem + 49152);

  const int tid = threadIdx.x, lane = tid & 63, w = tid >> 6;
  const int l31 = lane & 31, hi = lane >> 5;
  const int head = blockIdx.x & 7, qb = blockIdx.x >> 3;
  const size_t hoff = (size_t)head * S_ * PD_;
  const short* Qh = Qw + hoff;
  const short* Kh = Kw + hoff;
  const short* Vh = Vt + hoff;                 // [PD][S], pre-swizzled 32-granule
  const int wbase = tid & ~63;
  const int kh = w >> 1;
  const int kbase = kh * 2048;

  short* sKh = kh ? sK1 : sK0;
  short* sVh = kh ? sV1 : sV0;

  // Q fragments (B-operand of swapped QK)
  const int qrow = qb * 64 + (w & 1) * 32 + l31;
  short8 qf[16];
#pragma unroll
  for (int dc = 0; dc < 16; ++dc)
    qf[dc] = *(const short8*)(Qh + (size_t)qrow * PD_ + dc * 16 + hi * 8);

  f32x16 o[8];
#pragma unroll
  for (int i = 0; i < 8; ++i) o[i] = (f32x16)0.0f;
  float mrun = -3.0e38f, lrun = 0.0f;

  auto stage = [&](int t) {
    const int k0 = t * 32;
#pragma unroll
    for (int i = 0; i < 4; ++i) {
      int s = tid + 256 * i;
      short* ldst = (short*)((char*)nullptr);
      (void)ldst;
      gload16(Kh + (size_t)(k0 + (s >> 5)) * PD_ + (s & 31) * 8,
              sK0 + (size_t)(wbase + 256 * i) * 8);
      gload16(Kh + (size_t)(2048 + k0 + (s >> 5)) * PD_ + (s & 31) * 8,
              sK1 + (size_t)(wbase + 256 * i) * 8);
      gload16(Vh + (size_t)(s >> 2) * S_ + k0 + (s & 3) * 8,
              sV0 + (size_t)(wbase + 256 * i) * 8);
      gload16(Vh + (size_t)(s >> 2) * S_ + 2048 + k0 + (s & 3) * 8,
              sV1 + (size_t)(wbase + 256 * i) * 8);
    }
  };

#pragma unroll 1
  for (int t = 0; t < 64; ++t) {
    __syncthreads();             // everyone done reading previous tile
    stage(t);
    __syncthreads();             // implicit vmcnt(0): tiles staged

    // ---- QK^T (swapped): St[key 32][q 32]
    f32x16 sacc = (f32x16)0.0f;
#pragma unroll
    for (int dc = 0; dc < 16; ++dc) {
      int ch = (2 * dc + hi) ^ (l31 & 7);
      short8 kf = *(const short8*)&sKh[l31 * 256 + ch * 8];
      sacc = __builtin_amdgcn_mfma_f32_32x32x16_bf16(kf, qf[dc], sacc, 0, 0, 0);
    }

    // ---- online softmax (lane holds all 32 key-scores of q=l31 split over hi)
    float tmax = sacc[0];
#pragma unroll
    for (int r = 1; r < 16; ++r) tmax = fmaxf(tmax, sacc[r]);
    tmax = fmaxf(tmax, __shfl_xor(tmax, 32));
    if (!__all(tmax <= mrun + 16.0f)) {        // defer-max THR=16
      float mn = fmaxf(mrun, tmax);
      float resc = exp2f((mrun - mn) * SC2);
      mrun = mn;
      lrun *= resc;
      if (!hi) sB1[w][l31] = resc;
      asm volatile("" ::: "memory");
      f32x4 rv0 = *(const f32x4*)&sB1[w][0 + hi * 4];
      f32x4 rv1 = *(const f32x4*)&sB1[w][8 + hi * 4];
      f32x4 rv2 = *(const f32x4*)&sB1[w][16 + hi * 4];
      f32x4 rv3 = *(const f32x4*)&sB1[w][24 + hi * 4];
#pragma unroll
      for (int dcb = 0; dcb < 8; ++dcb)
#pragma unroll
        for (int r = 0; r < 16; ++r) {
          float rr = (r < 4 ? rv0 : r < 8 ? rv1 : r < 12 ? rv2 : rv3)[r & 3];
          o[dcb][r] *= rr;
        }
    }
    float lsum = 0.0f;
#pragma unroll
    for (int r = 0; r < 16; ++r) {
      float p = exp2f((sacc[r] - mrun) * SC2);
      sacc[r] = p;
      lsum += p;
    }
    lsum += __shfl_xor(lsum, 32);
    lrun += lsum;

    // ---- P repack (bf16, cross-hi exchange) + PV
#pragma unroll
    for (int c = 0; c < 2; ++c) {
      unsigned pk0 = pack2(sacc[8 * c + 0], sacc[8 * c + 1]);
      unsigned pk1 = pack2(sacc[8 * c + 2], sacc[8 * c + 3]);
      unsigned pk2 = pack2(sacc[8 * c + 4], sacc[8 * c + 5]);
      unsigned pk3 = pack2(sacc[8 * c + 6], sacc[8 * c + 7]);
      unsigned sh0 = __shfl_xor(pk0, 32);
      unsigned sh1 = __shfl_xor(pk1, 32);
      unsigned sh2 = __shfl_xor(pk2, 32);
      unsigned sh3 = __shfl_xor(pk3, 32);
      u32x4 ua;
      ua[0] = hi ? sh2 : pk0;
      ua[1] = hi ? sh3 : pk1;
      ua[2] = hi ? pk2 : sh0;
      ua[3] = hi ? pk3 : sh1;
      short8 af = *(short8*)&ua;
      const int ch = (2 * c + hi) ^ ((l31 >> 1) & 3);   // d-invariant
#pragma unroll
      for (int dcb = 0; dcb < 8; ++dcb) {
        short8 vf = *(const short8*)&sVh[(size_t)(dcb * 32 + l31) * 32 + ch * 8];
        o[dcb] = __builtin_amdgcn_mfma_f32_32x32x16_bf16(af, vf, o[dcb], 0, 0, 0);
      }
    }
  }

  // ---- in-block merge of key-half pairs (w <-> w^2 share q-rows) ----
  __syncthreads();
  if (!hi) sMm[w][l31] = mrun;
  __syncthreads();
  {
    float mo = sMm[w ^ 2][l31];
    float mf = fmaxf(mrun, mo);
    float sc = exp2f((mrun - mf) * SC2);
    lrun *= sc;
    if (!hi) sB1[w][l31] = sc;
    asm volatile("" ::: "memory");
    f32x4 rv0 = *(const f32x4*)&sB1[w][0 + hi * 4];
    f32x4 rv1 = *(const f32x4*)&sB1[w][8 + hi * 4];
    f32x4 rv2 = *(const f32x4*)&sB1[w][16 + hi * 4];
    f32x4 rv3 = *(const f32x4*)&sB1[w][24 + hi * 4];
#pragma unroll
    for (int dcb = 0; dcb < 8; ++dcb)
#pragma unroll
      for (int r = 0; r < 16; ++r) {
        float rr = (r < 4 ? rv0 : r < 8 ? rv1 : r < 12 ? rv2 : rv3)[r & 3];
        o[dcb][r] *= rr;
      }
    if (w >= 2 && !hi) sMl[w - 2][l31] = lrun;
  }
  __syncthreads();
  float* mb = (float*)smem;
  if (w >= 2) {                              // deposit scaled o
    float* rg = mb + (size_t)(w - 2) * 8320;
#pragma unroll
    for (int dcb = 0; dcb < 8; ++dcb)
#pragma unroll
      for (int r4 = 0; r4 < 4; ++r4) {
        f32x4 v;
        v[0] = o[dcb][4 * r4 + 0];
        v[1] = o[dcb][4 * r4 + 1];
        v[2] = o[dcb][4 * r4 + 2];
        v[3] = o[dcb][4 * r4 + 3];
        *(f32x4*)&rg[(size_t)(dcb * 4 + r4) * 260 + lane * 4] = v;
      }
  }
  __syncthreads();
  if (w < 2) {                               // combine + epilogue
    float* rg = mb + (size_t)w * 8320;
#pragma unroll
    for (int dcb = 0; dcb < 8; ++dcb)
#pragma unroll
      for (int r4 = 0; r4 < 4; ++r4) {
        f32x4 v = *(const f32x4*)&rg[(size_t)(dcb * 4 + r4) * 260 + lane * 4];
        o[dcb][4 * r4 + 0] += v[0];
        o[dcb][4 * r4 + 1] += v[1];
        o[dcb][4 * r4 + 2] += v[2];
        o[dcb][4 * r4 + 3] += v[3];
      }
    lrun += sMl[w][l31];
    if (!hi) sB1[w][l31] = 1.0f / lrun;
    asm volatile("" ::: "memory");
    f32x4 iv0 = *(const f32x4*)&sB1[w][0 + hi * 4];
    f32x4 iv1 = *(const f32x4*)&sB1[w][8 + hi * 4];
    f32x4 iv2 = *(const f32x4*)&sB1[w][16 + hi * 4];
    f32x4 iv3 = *(const f32x4*)&sB1[w][24 + hi * 4];
    const int bb = head >> 1, hh = head & 1;
#pragma unroll
    for (int r = 0; r < 16; ++r) {
      int q = qb * 64 + (w & 1) * 32 + (r & 3) + 8 * (r >> 2) + 4 * hi;
      float iv = (r < 4 ? iv0 : r < 8 ? iv1 : r < 12 ? iv2 : iv3)[r & 3];
      size_t base = ((size_t)(bb * S_ + q)) * D_ + hh * PD_;
#pragma unroll
      for (int dcb = 0; dcb < 8; ++dcb)
        ATT[base + dcb * 32 + l31] = f2bf(o[dcb][r] * iv);
    }
  }
}

// ---------------- launcher ----------------
extern "C" void kernel_launch(void* const* d_in, const int* in_sizes, int n_in,
                              void* d_out, int out_size, void* d_ws, size_t ws_size,
                              hipStream_t stream) {
  const float* x  = (const float*)d_in[0];
  const float* Wq = (const float*)d_in[1];
  const float* bq = (const float*)d_in[2];
  const float* Wk = (const float*)d_in[3];
  const float* bk = (const float*)d_in[4];
  const float* Wv = (const float*)d_in[5];
  const float* bv = (const float*)d_in[6];
  const float* Wo = (const float*)d_in[7];
  const float* bo = (const float*)d_in[8];
  float* out = (float*)d_out;

  char* ws = (char*)d_ws;
  const size_t WSZ = (size_t)D_ * D_ * 2;             // 512KB per transposed weight
  const size_t QSZ = (size_t)B_ * H_ * S_ * PD_ * 2;  // 16.78MB
  short* wtq = (short*)(ws);
  short* wtk = (short*)(ws + WSZ);
  short* wtv = (short*)(ws + 2 * WSZ);
  short* wto = (short*)(ws + 3 * WSZ);
  short* Qw  = (short*)(ws + 4 * WSZ);
  short* Kw  = (short*)(ws + 4 * WSZ + QSZ);
  short* Vw  = (short*)(ws + 4 * WSZ + 2 * QSZ);
  short* ATT = (short*)(ws + 4 * WSZ + 3 * QSZ);  // also used as xb (dead before attn writes)
  short* XB  = ATT;
  short* Vtp = (short*)d_out;  // V^T scratch lives in d_out; overwritten by final GEMM

  convert_x_kernel<<<dim3(2048), dim3(256), 0, stream>>>(x, XB, (B_ * S_ * D_) / 8);
  transpose_w<<<dim3(16, 16, 4), dim3(256), 0, stream>>>(Wq, Wk, Wv, Wo, wtq, wtk, wtv, wto);
  gemm_bt<0><<<dim3(128, 4, 3), dim3(256), 0, stream>>>(
      XB, wtq, wtk, wtv, bq, bk, bv, Qw, Kw, Vw, (float*)nullptr);
  transpose_v<<<dim3(64, 4, 8), dim3(256), 0, stream>>>(Vw, Vtp);
  attn3_kernel<<<dim3(512), dim3(256), 0, stream>>>(Qw, Kw, Vtp, ATT);
  gemm_bt<1><<<dim3(128, 4, 1), dim3(256), 0, stream>>>(
      ATT, wto, wto, wto, bo, bo, bo, nullptr, nullptr, nullptr, out);
}

// Round 4
// 290.239 us; speedup vs baseline: 1.4952x; 1.0081x over previous
//
#include <hip/hip_runtime.h>
#include <hip/hip_bf16.h>

// MultiHeadAttention: B=4, S=4096, D=512, H=2, PD=256, fp32 in/out.
// R4: 8-wave attn (split-K-2 x 4 q-groups), double-buffered BK=32 staging with
// single barrier/iter (stage overlaps compute), precomputed swizzled LDS addrs
// (4+2 VGPRs, immediates for dc/dcb/buf), cvt_pk bf16 pack, Q pre-scaled by
// (1/16)*log2(e) in the QKV GEMM, defer-max THR=8 (log2 units).

#define B_  4
#define S_  4096
#define D_  512
#define H_  2
#define PD_ 256
#define QSCALE 0.09016844f   // (1/sqrt(256)) * log2(e)

typedef __attribute__((ext_vector_type(4))) float f32x4;
typedef __attribute__((ext_vector_type(16))) float f32x16;
typedef __attribute__((ext_vector_type(8))) short short8;
typedef __attribute__((ext_vector_type(4))) short short4v;
typedef __attribute__((ext_vector_type(4))) unsigned u32x4;

static __device__ __forceinline__ short f2bf(float f) {
  unsigned u = __float_as_uint(f);
  u += 0x7fffu + ((u >> 16) & 1u);
  return (short)(u >> 16);
}
static __device__ __forceinline__ unsigned cvtpk(float a, float b) {
  unsigned r;
  asm("v_cvt_pk_bf16_f32 %0, %1, %2" : "=v"(r) : "v"(a), "v"(b));
  return r;
}
static __device__ __forceinline__ void gload16(const short* g, const short* l) {
  __builtin_amdgcn_global_load_lds((const __attribute__((address_space(1))) void*)g,
                                   (__attribute__((address_space(3))) void*)l,
                                   16, 0, 0);
}

// ---------------- kernel: convert x (f32) -> bf16 ----------------
__global__ void convert_x_kernel(const float* __restrict__ x, short* __restrict__ xb, int n8) {
  int i = blockIdx.x * blockDim.x + threadIdx.x;
  int stride = gridDim.x * blockDim.x;
  for (; i < n8; i += stride) {
    const f32x4* p = (const f32x4*)(x + (size_t)i * 8);
    f32x4 a = p[0], b = p[1];
    short8 v;
    v[0] = f2bf(a[0]); v[1] = f2bf(a[1]); v[2] = f2bf(a[2]); v[3] = f2bf(a[3]);
    v[4] = f2bf(b[0]); v[5] = f2bf(b[1]); v[6] = f2bf(b[2]); v[7] = f2bf(b[3]);
    *(short8*)(xb + (size_t)i * 8) = v;
  }
}

// ---------------- kernel: transpose W[k][n] f32 -> Wt[n][k] bf16 ----------------
__global__ __launch_bounds__(256) void transpose_w(
    const float* __restrict__ W0, const float* __restrict__ W1,
    const float* __restrict__ W2, const float* __restrict__ W3,
    short* __restrict__ T0, short* __restrict__ T1,
    short* __restrict__ T2, short* __restrict__ T3) {
  const float* W = (blockIdx.z == 0) ? W0 : (blockIdx.z == 1) ? W1 : (blockIdx.z == 2) ? W2 : W3;
  short* T = (blockIdx.z == 0) ? T0 : (blockIdx.z == 1) ? T1 : (blockIdx.z == 2) ? T2 : T3;
  __shared__ float tile[32][33];
  int tx = threadIdx.x & 31, ty = threadIdx.x >> 5;
  int r0 = blockIdx.x * 32, c0 = blockIdx.y * 32;
#pragma unroll
  for (int i = 0; i < 4; ++i)
    tile[ty + 8 * i][tx] = W[(size_t)(r0 + ty + 8 * i) * D_ + c0 + tx];
  __syncthreads();
#pragma unroll
  for (int i = 0; i < 4; ++i)
    T[(size_t)(c0 + ty + 8 * i) * D_ + r0 + tx] = f2bf(tile[tx][ty + 8 * i]);
}

// ---------------- kernel: transpose V (bf16) -> Vt[h][d][s] ----------------
// chunk-XOR pre-swizzle within each 32-key granule: slot = ((s>>3)&3) ^ ((d>>3)&3)
__global__ __launch_bounds__(256) void transpose_v(
    const short* __restrict__ Vw, short* __restrict__ Vt) {
  __shared__ short tile[64][68];
  int h = blockIdx.z;
  int s0 = blockIdx.x * 64, d0 = blockIdx.y * 64;
  const short* src = Vw + (size_t)h * S_ * PD_;
  short* dst = Vt + (size_t)h * S_ * PD_;
  int tx = threadIdx.x & 15, ty = threadIdx.x >> 4;
#pragma unroll
  for (int i = 0; i < 4; ++i) {
    short4v v = *(const short4v*)(src + (size_t)(s0 + ty + 16 * i) * PD_ + d0 + tx * 4);
    *(short4v*)&tile[ty + 16 * i][tx * 4] = v;
  }
  __syncthreads();
#pragma unroll
  for (int i = 0; i < 4; ++i) {
    int d = d0 + ty + 16 * i;
    short4v v;
#pragma unroll
    for (int j = 0; j < 4; ++j) v[j] = tile[tx * 4 + j][ty + 16 * i];
    int swz = ((tx >> 1) & 3) ^ ((d >> 3) & 3);   // chunk slot within 32-granule
    *(short4v*)(dst + (size_t)d * S_ + s0 + (tx >> 3) * 32 + swz * 8 + (tx & 1) * 4) = v;
  }
}

// ---------------- GEMM: C[M,N] = A[M,512](bf16) * Bt[N,512](bf16)^T + bias ----------------
// MODE 0: z=0 Q (scaled by QSCALE), z=1 K (chunk-XOR pre-swizzled), z=2 V.
// MODE 1: single weight, dense f32 out + bias.
template <int MODE>
__global__ __launch_bounds__(256, 2) void gemm_bt(
    const short* __restrict__ A,
    const short* __restrict__ Bt0, const short* __restrict__ Bt1, const short* __restrict__ Bt2,
    const float* __restrict__ b0, const float* __restrict__ b1, const float* __restrict__ b2,
    short* __restrict__ o0, short* __restrict__ o1, short* __restrict__ o2,
    float* __restrict__ fout) {
  __shared__ short sA[128 * 72];
  __shared__ short sB[128 * 72];

  const int tid = threadIdx.x;
  const int lane = tid & 63, wid = tid >> 6;
  const int wr = wid >> 1, wc = wid & 1;
  const int l15 = lane & 15, g = lane >> 4;
  const int m0 = blockIdx.x * 128, n0 = blockIdx.y * 128;

  const short* Bt = (MODE == 0) ? ((blockIdx.z == 0) ? Bt0 : (blockIdx.z == 1) ? Bt1 : Bt2) : Bt0;
  const float* bias = (MODE == 0) ? ((blockIdx.z == 0) ? b0 : (blockIdx.z == 1) ? b1 : b2) : b0;

  short8 pa[4], pb[4];

  auto loadT = [&](int kt) {
#pragma unroll
    for (int i = 0; i < 4; ++i) {
      int slot = tid + 256 * i;
      int r = slot >> 3, gg = slot & 7;
      pa[i] = *(const short8*)(A + (size_t)(m0 + r) * D_ + kt * 64 + 8 * gg);
      pb[i] = *(const short8*)(Bt + (size_t)(n0 + r) * D_ + kt * 64 + 8 * gg);
    }
  };
  auto storeT = [&]() {
#pragma unroll
    for (int i = 0; i < 4; ++i) {
      int slot = tid + 256 * i;
      int r = slot >> 3, gg = slot & 7;
      *(short8*)&sA[r * 72 + 8 * gg] = pa[i];
      *(short8*)&sB[r * 72 + 8 * gg] = pb[i];
    }
  };

  f32x4 acc[4][4];
#pragma unroll
  for (int i = 0; i < 4; ++i)
#pragma unroll
    for (int j = 0; j < 4; ++j) acc[i][j] = (f32x4)0.0f;

  loadT(0);
#pragma unroll 1
  for (int kt = 0; kt < 8; ++kt) {
    __syncthreads();
    storeT();
    if (kt < 7) loadT(kt + 1);
    __syncthreads();
#pragma unroll
    for (int s = 0; s < 2; ++s) {
      short8 a[4], b[4];
#pragma unroll
      for (int fr = 0; fr < 4; ++fr)
        a[fr] = *(const short8*)&sA[(wr * 64 + fr * 16 + l15) * 72 + 32 * s + 8 * g];
#pragma unroll
      for (int fc = 0; fc < 4; ++fc)
        b[fc] = *(const short8*)&sB[(wc * 64 + fc * 16 + l15) * 72 + 32 * s + 8 * g];
#pragma unroll
      for (int fr = 0; fr < 4; ++fr)
#pragma unroll
        for (int fc = 0; fc < 4; ++fc)
          acc[fr][fc] = __builtin_amdgcn_mfma_f32_16x16x32_bf16(a[fr], b[fc], acc[fr][fc], 0, 0, 0);
    }
  }

  if (MODE == 0) {
    short* dst = (blockIdx.z == 0) ? o0 : (blockIdx.z == 1) ? o1 : o2;
    const bool kswz = (blockIdx.z == 1);
    const float sc = (blockIdx.z == 0) ? QSCALE : 1.0f;
#pragma unroll
    for (int fc = 0; fc < 4; ++fc) {
      int n = n0 + wc * 64 + fc * 16 + l15;
      float bvv = bias[n];
      int h = n >> 8, pd = n & 255;
#pragma unroll
      for (int fr = 0; fr < 4; ++fr)
#pragma unroll
        for (int r = 0; r < 4; ++r) {
          int m = m0 + wr * 64 + fr * 16 + 4 * g + r;
          int bb = m >> 12, ss = m & 4095;
          int pdw = pd;
          if (kswz) {
            int ch = pd >> 3;
            pdw = (pd & 7) | (((ch & 24) | ((ch & 7) ^ (ss & 7))) << 3);
          }
          dst[((size_t)((bb * H_ + h) * S_ + ss)) * PD_ + pdw] = f2bf((acc[fr][fc][r] + bvv) * sc);
        }
    }
  } else {
#pragma unroll
    for (int fc = 0; fc < 4; ++fc) {
      int n = n0 + wc * 64 + fc * 16 + l15;
      float bvv = bias[n];
#pragma unroll
      for (int fr = 0; fr < 4; ++fr)
#pragma unroll
        for (int r = 0; r < 4; ++r) {
          int m = m0 + wr * 64 + fr * 16 + 4 * g + r;
          fout[(size_t)m * D_ + n] = acc[fr][fc][r] + bvv;
        }
    }
  }
}

// ---------------- flash attention, 8-wave split-K-2 double-buffered ----------------
// Block: 512 thr = 8 waves; wave w: key-half kh=w>>2, q-group qg=w&3 (32 q).
// 128 q/block. BK=32/half, double-buffered (128KB LDS). One barrier per iter;
// stage(t+1) issued right after, drained by next barrier's implicit vmcnt(0).
// LDS layout: K: [half][buf][32key][32 swz chunks of 16B]  (0..65535)
//             V: 65536 + [half][buf][256d][4 swz chunks of 16B]
__global__ __launch_bounds__(512, 2) void attn4_kernel(
    const short* __restrict__ Qw, const short* __restrict__ Kw,
    const short* __restrict__ Vt, short* __restrict__ ATT) {
  __shared__ __align__(16) char smem[133120];  // staging 128KB; merge 4x33280B
  __shared__ float sMm[8][32];
  __shared__ float sB1[8][32];
  __shared__ float sMl[4][32];

  const int tid = threadIdx.x, lane = tid & 63, w = tid >> 6;
  const int l31 = lane & 31, hi = lane >> 5;
  const int head = blockIdx.x & 7, qb = blockIdx.x >> 3;
  const int kh = w >> 2, qg = w & 3;
  const size_t hoff = (size_t)head * S_ * PD_;
  const short* Qh = Qw + hoff;
  const short* Kh = Kw + hoff;
  const short* Vh = Vt + hoff;                 // [PD][S], pre-swizzled 32-granule

  // Q fragments (B-operand of swapped QK); Q already has QSCALE folded in.
  const int qrow = qb * 128 + qg * 32 + l31;
  short8 qf[16];
#pragma unroll
  for (int dc = 0; dc < 16; ++dc)
    qf[dc] = *(const short8*)(Qh + (size_t)qrow * PD_ + dc * 16 + hi * 8);

  // precomputed swizzled LDS read addresses
  const int mm = l31 & 7, pp = (l31 >> 1) & 3, q3 = l31 >> 3;
  int kaddr[4];
#pragma unroll
  for (int b = 0; b < 4; ++b)
    kaddr[b] = kh * 32768 + l31 * 512 + ((b ^ pp) << 5) + ((hi ^ (mm & 1)) << 4);
  int vaddr[2];
#pragma unroll
  for (int c = 0; c < 2; ++c)
    vaddr[c] = 65536 + kh * 32768 + l31 * 64 + (((2 * c + hi) ^ q3) << 4);

  f32x16 o[8];
#pragma unroll
  for (int i = 0; i < 8; ++i) o[i] = (f32x16)0.0f;
  float mrun = -3.0e38f, lrun = 0.0f;

  auto stage = [&](int buf, int t) {
    const short* kt = Kh + (size_t)(t * 32) * PD_;
#pragma unroll
    for (int i = 0; i < 4; ++i) {
      int s = tid + 512 * i;                  // 0..2047
      int half = s >> 10, s1 = s & 1023;      // s1: key=s1>>5, chunk=s1&31
      gload16(kt + (size_t)(half * 2048) * PD_ + (s1 >> 5) * PD_ + (s1 & 31) * 8,
              (const short*)(smem + half * 32768 + buf * 16384 + s1 * 16));
    }
    const short* vt = Vh + t * 32;
#pragma unroll
    for (int i = 0; i < 4; ++i) {
      int s = tid + 512 * i;
      int half = s >> 10, s1 = s & 1023;      // s1: d=s1>>2, chunk=s1&3
      gload16(vt + (size_t)(s1 >> 2) * S_ + half * 2048 + (s1 & 3) * 8,
              (const short*)(smem + 65536 + half * 32768 + buf * 16384 + s1 * 16));
    }
  };

  auto compute = [&](int buf) {
    // ---- QK^T (swapped): St[key 32][q 32], dual accumulators
    f32x16 sa = (f32x16)0.0f, sb = (f32x16)0.0f;
#pragma unroll
    for (int a = 0; a < 4; ++a)
#pragma unroll
      for (int b = 0; b < 4; ++b) {
        short8 kf = *(const short8*)(smem + kaddr[b] + a * 128 + buf * 16384);
        if (a < 2)
          sa = __builtin_amdgcn_mfma_f32_32x32x16_bf16(kf, qf[4 * a + b], sa, 0, 0, 0);
        else
          sb = __builtin_amdgcn_mfma_f32_32x32x16_bf16(kf, qf[4 * a + b], sb, 0, 0, 0);
      }
    f32x16 sacc = sa + sb;

    // ---- online softmax (scores already in log2 units)
    float tmax = fmaxf(sacc[0], sacc[1]);
#pragma unroll
    for (int r = 2; r < 16; ++r) tmax = fmaxf(tmax, sacc[r]);
    tmax = fmaxf(tmax, __shfl_xor(tmax, 32));
    if (!__all(tmax <= mrun + 8.0f)) {         // defer-max THR=8 (log2)
      float mn = fmaxf(mrun, tmax);
      float resc = exp2f(mrun - mn);
      mrun = mn;
      lrun *= resc;
      if (!hi) sB1[w][l31] = resc;
      asm volatile("" ::: "memory");
      f32x4 rv0 = *(const f32x4*)&sB1[w][0 + hi * 4];
      f32x4 rv1 = *(const f32x4*)&sB1[w][8 + hi * 4];
      f32x4 rv2 = *(const f32x4*)&sB1[w][16 + hi * 4];
      f32x4 rv3 = *(const f32x4*)&sB1[w][24 + hi * 4];
#pragma unroll
      for (int dcb = 0; dcb < 8; ++dcb)
#pragma unroll
        for (int r = 0; r < 16; ++r) {
          float rr = (r < 4 ? rv0 : r < 8 ? rv1 : r < 12 ? rv2 : rv3)[r & 3];
          o[dcb][r] *= rr;
        }
    }
    float lsum = 0.0f;
#pragma unroll
    for (int r = 0; r < 16; ++r) {
      float pv = exp2f(sacc[r] - mrun);
      sacc[r] = pv;
      lsum += pv;
    }
    lsum += __shfl_xor(lsum, 32);
    lrun += lsum;

    // ---- P repack (cvt_pk bf16, cross-hi exchange) + PV
#pragma unroll
    for (int c = 0; c < 2; ++c) {
      unsigned pk0 = cvtpk(sacc[8 * c + 0], sacc[8 * c + 1]);
      unsigned pk1 = cvtpk(sacc[8 * c + 2], sacc[8 * c + 3]);
      unsigned pk2 = cvtpk(sacc[8 * c + 4], sacc[8 * c + 5]);
      unsigned pk3 = cvtpk(sacc[8 * c + 6], sacc[8 * c + 7]);
      unsigned sh0 = __shfl_xor(pk0, 32);
      unsigned sh1 = __shfl_xor(pk1, 32);
      unsigned sh2 = __shfl_xor(pk2, 32);
      unsigned sh3 = __shfl_xor(pk3, 32);
      u32x4 ua;
      ua[0] = hi ? sh2 : pk0;
      ua[1] = hi ? sh3 : pk1;
      ua[2] = hi ? pk2 : sh0;
      ua[3] = hi ? pk3 : sh1;
      short8 af = *(short8*)&ua;
#pragma unroll
      for (int dcb = 0; dcb < 8; ++dcb) {
        short8 vf = *(const short8*)(smem + vaddr[c] + dcb * 2048 + buf * 16384);
        o[dcb] = __builtin_amdgcn_mfma_f32_32x32x16_bf16(af, vf, o[dcb], 0, 0, 0);
      }
    }
  };

  stage(0, 0);
#pragma unroll 1
  for (int t = 0; t < 64; t += 2) {
    __syncthreads();               // buf0 staged; all waves done reading buf1
    stage(1, t + 1);
    compute(0);
    __syncthreads();               // buf1 staged; all waves done reading buf0
    if (t + 2 < 64) stage(0, t + 2);
    compute(1);
  }

  // ---- merge key-half pairs (w <-> w^4 share q-rows) ----
  __syncthreads();
  if (!hi) sMm[w][l31] = mrun;
  __syncthreads();
  {
    float mo = sMm[w ^ 4][l31];
    float mf = fmaxf(mrun, mo);
    float sc = exp2f(mrun - mf);
    lrun *= sc;
    if (!hi) sB1[w][l31] = sc;
    asm volatile("" ::: "memory");
    f32x4 rv0 = *(const f32x4*)&sB1[w][0 + hi * 4];
    f32x4 rv1 = *(const f32x4*)&sB1[w][8 + hi * 4];
    f32x4 rv2 = *(const f32x4*)&sB1[w][16 + hi * 4];
    f32x4 rv3 = *(const f32x4*)&sB1[w][24 + hi * 4];
#pragma unroll
    for (int dcb = 0; dcb < 8; ++dcb)
#pragma unroll
      for (int r = 0; r < 16; ++r) {
        float rr = (r < 4 ? rv0 : r < 8 ? rv1 : r < 12 ? rv2 : rv3)[r & 3];
        o[dcb][r] *= rr;
      }
    if (w >= 4 && !hi) sMl[w - 4][l31] = lrun;
  }
  __syncthreads();
  float* mb = (float*)smem;
  if (w >= 4) {                              // deposit scaled o
    float* rg = mb + (size_t)qg * 8320;
#pragma unroll
    for (int dcb = 0; dcb < 8; ++dcb)
#pragma unroll
      for (int r4 = 0; r4 < 4; ++r4) {
        f32x4 v;
        v[0] = o[dcb][4 * r4 + 0];
        v[1] = o[dcb][4 * r4 + 1];
        v[2] = o[dcb][4 * r4 + 2];
        v[3] = o[dcb][4 * r4 + 3];
        *(f32x4*)&rg[(size_t)(dcb * 4 + r4) * 260 + lane * 4] = v;
      }
  }
  __syncthreads();
  if (w < 4) {                               // combine + epilogue
    float* rg = mb + (size_t)qg * 8320;
#pragma unroll
    for (int dcb = 0; dcb < 8; ++dcb)
#pragma unroll
      for (int r4 = 0; r4 < 4; ++r4) {
        f32x4 v = *(const f32x4*)&rg[(size_t)(dcb * 4 + r4) * 260 + lane * 4];
        o[dcb][4 * r4 + 0] += v[0];
        o[dcb][4 * r4 + 1] += v[1];
        o[dcb][4 * r4 + 2] += v[2];
        o[dcb][4 * r4 + 3] += v[3];
      }
    lrun += sMl[qg][l31];
    if (!hi) sB1[w][l31] = 1.0f / lrun;
    asm volatile("" ::: "memory");
    f32x4 iv0 = *(const f32x4*)&sB1[w][0 + hi * 4];
    f32x4 iv1 = *(const f32x4*)&sB1[w][8 + hi * 4];
    f32x4 iv2 = *(const f32x4*)&sB1[w][16 + hi * 4];
    f32x4 iv3 = *(const f32x4*)&sB1[w][24 + hi * 4];
    const int bb = head >> 1, hh = head & 1;
#pragma unroll
    for (int r = 0; r < 16; ++r) {
      int q = qb * 128 + qg * 32 + (r & 3) + 8 * (r >> 2) + 4 * hi;
      float iv = (r < 4 ? iv0 : r < 8 ? iv1 : r < 12 ? iv2 : iv3)[r & 3];
      size_t base = ((size_t)(bb * S_ + q)) * D_ + hh * PD_;
#pragma unroll
      for (int dcb = 0; dcb < 8; ++dcb)
        ATT[base + dcb * 32 + l31] = f2bf(o[dcb][r] * iv);
    }
  }
}

// ---------------- launcher ----------------
extern "C" void kernel_launch(void* const* d_in, const int* in_sizes, int n_in,
                              void* d_out, int out_size, void* d_ws, size_t ws_size,
                              hipStream_t stream) {
  const float* x  = (const float*)d_in[0];
  const float* Wq = (const float*)d_in[1];
  const float* bq = (const float*)d_in[2];
  const float* Wk = (const float*)d_in[3];
  const float* bk = (const float*)d_in[4];
  const float* Wv = (const float*)d_in[5];
  const float* bv = (const float*)d_in[6];
  const float* Wo = (const float*)d_in[7];
  const float* bo = (const float*)d_in[8];
  float* out = (float*)d_out;

  char* ws = (char*)d_ws;
  const size_t WSZ = (size_t)D_ * D_ * 2;             // 512KB per transposed weight
  const size_t QSZ = (size_t)B_ * H_ * S_ * PD_ * 2;  // 16.78MB
  short* wtq = (short*)(ws);
  short* wtk = (short*)(ws + WSZ);
  short* wtv = (short*)(ws + 2 * WSZ);
  short* wto = (short*)(ws + 3 * WSZ);
  short* Qw  = (short*)(ws + 4 * WSZ);
  short* Kw  = (short*)(ws + 4 * WSZ + QSZ);
  short* Vw  = (short*)(ws + 4 * WSZ + 2 * QSZ);
  short* ATT = (short*)(ws + 4 * WSZ + 3 * QSZ);  // also used as xb (dead before attn writes)
  short* XB  = ATT;
  short* Vtp = (short*)d_out;  // V^T scratch lives in d_out; overwritten by final GEMM

  convert_x_kernel<<<dim3(2048), dim3(256), 0, stream>>>(x, XB, (B_ * S_ * D_) / 8);
  transpose_w<<<dim3(16, 16, 4), dim3(256), 0, stream>>>(Wq, Wk, Wv, Wo, wtq, wtk, wtv, wto);
  gemm_bt<0><<<dim3(128, 4, 3), dim3(256), 0, stream>>>(
      XB, wtq, wtk, wtv, bq, bk, bv, Qw, Kw, Vw, (float*)nullptr);
  transpose_v<<<dim3(64, 4, 8), dim3(256), 0, stream>>>(Vw, Vtp);
  attn4_kernel<<<dim3(256), dim3(512), 0, stream>>>(Qw, Kw, Vtp, ATT);
  gemm_bt<1><<<dim3(128, 4, 1), dim3(256), 0, stream>>>(
      ATT, wto, wto, wto, bo, bo, bo, nullptr, nullptr, nullptr, out);
}